// Round 7
// baseline (343.603 us; speedup 1.0000x reference)
//
#include <hip/hip_runtime.h>

#define B_ 256
#define L_ 512
#define D_ 768
#define C_ 10331
#define K_ 2304           // 3*D
#define GBK 64
#define NKIT (K_ / GBK)   // 36
#define LDPA 72           // padded LDS row (bf16 elems)

using v8bf = __attribute__((ext_vector_type(8))) __bf16;
using v4f  = __attribute__((ext_vector_type(4))) float;

__device__ __forceinline__ unsigned short f2bf(float f) {
    unsigned int u = __float_as_uint(f);
    unsigned int r = (u + 0x7FFFu + ((u >> 16) & 1u)) >> 16;   // RNE
    return (unsigned short)r;
}

__device__ __forceinline__ void fma4(float4& a, float w, const float4& v) {
    a.x = fmaf(w, v.x, a.x); a.y = fmaf(w, v.y, a.y);
    a.z = fmaf(w, v.z, a.z); a.w = fmaf(w, v.w, a.w);
}

// ---------------------------------------------------------------------------
// Kernel 1: count-based gather + masked means -> feats (B, 3D) bf16.
// MEASUREMENT BUILD: streaming pass runs 2x with weights pre-scaled by 0.5
// (both passes live -> no DCE; result identical up to fp associativity).
// ---------------------------------------------------------------------------
__global__ __launch_bounds__(512) void feats_gather(
    const float* __restrict__ seq,        // (B, L, D)
    const int*   __restrict__ head_index, // (B, L)
    const int*   __restrict__ start,
    const int*   __restrict__ end,
    unsigned short* __restrict__ feats)   // (B, 3D) bf16
{
    const int b    = blockIdx.x;
    const int t    = threadIdx.x;
    const int lane = t & 63;
    const int wave = t >> 6;              // 0..7

    __shared__ int idx_sh[L_];
    __shared__ int cnt_sh[3][L_];
    __shared__ int list_sh[L_];
    __shared__ int nz_sh, nlist_sh;
    __shared__ float4 red_sh[8][3][192];  // 72 KB

    if (t == 0) nz_sh = 0;
    cnt_sh[0][t] = 0; cnt_sh[1][t] = 0; cnt_sh[2][t] = 0;
    const int v = head_index[b * L_ + t];
    idx_sh[t] = v;
    unsigned long long ball = __ballot(v != 0);
    __syncthreads();
    if (lane == 0) atomicAdd(&nz_sh, (int)__popcll(ball));
    __syncthreads();

    const int right_len = nz_sh;
    const int s = start[b];
    const int e = end[b];

    if (t < right_len) {
        int r = (t < s) ? 0 : ((t < e) ? 1 : 2);
        atomicAdd(&cnt_sh[r][v], 1);
    }
    __syncthreads();

    if (wave == 0) {
        int maskbits = 0, csum = 0;
        const int j0 = lane * 8;
        #pragma unroll
        for (int k = 0; k < 8; ++k) {
            int j = j0 + k;
            if (cnt_sh[0][j] | cnt_sh[1][j] | cnt_sh[2][j]) { maskbits |= (1 << k); ++csum; }
        }
        int incl = csum;
        #pragma unroll
        for (int off = 1; off < 64; off <<= 1) {
            int x = __shfl_up(incl, off, 64);
            if (lane >= off) incl += x;
        }
        int pos = incl - csum;
        #pragma unroll
        for (int k = 0; k < 8; ++k)
            if (maskbits & (1 << k)) list_sh[pos++] = j0 + k;
        if (lane == 63) nlist_sh = incl;
    }
    __syncthreads();

    const int nlist = nlist_sh;
    const int nl = s, nm = e - s, nr = right_len - e;
    // 0.5 factor: streaming pass below runs twice, both halves accumulate.
    const float rs0 = (nl > 0) ? 0.5f / (float)nl : 0.0f;
    const float rs1 = (nm > 0) ? 0.5f / (float)nm : 0.0f;
    const float rs2 = (nr > 0) ? 0.5f / (float)nr : 0.0f;

    const float4* seqb4 = reinterpret_cast<const float4*>(seq + (size_t)b * L_ * D_);

    float4 acc[3][3];
    #pragma unroll
    for (int r = 0; r < 3; ++r)
        #pragma unroll
        for (int jj = 0; jj < 3; ++jj)
            acc[r][jj] = make_float4(0.f, 0.f, 0.f, 0.f);

    for (int rep = 0; rep < 2; ++rep) {
        int i = wave;
        for (; i + 8 < nlist; i += 16) {
            const int ja = list_sh[i], jb = list_sh[i + 8];
            const float4* rowa = seqb4 + (size_t)ja * 192;
            const float4* rowb = seqb4 + (size_t)jb * 192;
            float wa0 = (float)cnt_sh[0][ja] * rs0;
            float wa1 = (float)cnt_sh[1][ja] * rs1;
            float wa2 = (float)cnt_sh[2][ja] * rs2;
            float wb0 = (float)cnt_sh[0][jb] * rs0;
            float wb1 = (float)cnt_sh[1][jb] * rs1;
            float wb2 = (float)cnt_sh[2][jb] * rs2;
            #pragma unroll
            for (int jj = 0; jj < 3; ++jj) {
                float4 va = rowa[jj * 64 + lane];
                float4 vb = rowb[jj * 64 + lane];
                fma4(acc[0][jj], wa0, va); fma4(acc[1][jj], wa1, va); fma4(acc[2][jj], wa2, va);
                fma4(acc[0][jj], wb0, vb); fma4(acc[1][jj], wb1, vb); fma4(acc[2][jj], wb2, vb);
            }
        }
        if (i < nlist) {
            const int ja = list_sh[i];
            const float4* rowa = seqb4 + (size_t)ja * 192;
            float wa0 = (float)cnt_sh[0][ja] * rs0;
            float wa1 = (float)cnt_sh[1][ja] * rs1;
            float wa2 = (float)cnt_sh[2][ja] * rs2;
            #pragma unroll
            for (int jj = 0; jj < 3; ++jj) {
                float4 va = rowa[jj * 64 + lane];
                fma4(acc[0][jj], wa0, va); fma4(acc[1][jj], wa1, va); fma4(acc[2][jj], wa2, va);
            }
        }
    }

    #pragma unroll
    for (int r = 0; r < 3; ++r)
        #pragma unroll
        for (int jj = 0; jj < 3; ++jj)
            red_sh[wave][r][jj * 64 + lane] = acc[r][jj];
    __syncthreads();

    for (int w = t; w < 576; w += 512) {
        int reg = w / 192, pos = w - reg * 192;
        float4 sum = red_sh[0][reg][pos];
        #pragma unroll
        for (int wv = 1; wv < 8; ++wv) {
            float4 x = red_sh[wv][reg][pos];
            sum.x += x.x; sum.y += x.y; sum.z += x.z; sum.w += x.w;
        }
        ushort4 u;
        u.x = f2bf(sum.x); u.y = f2bf(sum.y); u.z = f2bf(sum.z); u.w = f2bf(sum.w);
        *(ushort4*)(&feats[(size_t)b * K_ + reg * D_ + pos * 4]) = u;
    }
}

// ---------------------------------------------------------------------------
// Kernel 2: out = feats(bf16) @ W^T + bias.
// MEASUREMENT BUILD: the full K-loop runs 3x accumulating into the same acc
// (no DCE possible); epilogue scales by 1/3. Error ~1 ulp.
// ---------------------------------------------------------------------------
__global__ __launch_bounds__(512) void mfma_gemm(
    const unsigned short* __restrict__ A,  // (B_, K_) bf16
    const float* __restrict__ W,           // (C_, K_) fp32
    const float* __restrict__ bias,        // (C_,)
    float*       __restrict__ out)         // (B_, C_) f32
{
    __shared__ unsigned short As[256 * LDPA];
    __shared__ unsigned short Bs[64  * LDPA];

    const int t    = threadIdx.x;
    const int lane = t & 63;
    const int wave = t >> 6;
    const int wr   = wave >> 1;
    const int wc   = wave & 1;
    const int col0 = blockIdx.x * 64;

    const int frow = lane & 15;
    const int fk   = (lane >> 4) * 8;

    v4f acc[4][2] = {};
    int4   ra0[4], ra1[4];
    float4 rb0[2], rb1[2];

#define LOAD_A(dst, k0)                                                     \
    _Pragma("unroll")                                                       \
    for (int i = 0; i < 4; ++i) {                                           \
        int g = t + i * 512;                                                \
        int r = g >> 3, kg = (g & 7) * 8;                                   \
        dst[i] = *(const int4*)(A + (size_t)r * K_ + (k0) + kg);            \
    }
#define LOAD_B(dst, k0)                                                     \
    _Pragma("unroll")                                                       \
    for (int i = 0; i < 2; ++i) {                                           \
        int c = t + i * 512;                                                \
        int r = c >> 4, kq = (c & 15) * 4;                                  \
        int col = col0 + r;                                                 \
        dst[i] = (col < C_) ? *(const float4*)(W + (size_t)col * K_ + (k0) + kq) \
                            : make_float4(0.f, 0.f, 0.f, 0.f);              \
    }
#define WRITE_LDS(sa, sb)                                                   \
    _Pragma("unroll")                                                       \
    for (int i = 0; i < 4; ++i) {                                           \
        int g = t + i * 512;                                                \
        int r = g >> 3, kg = (g & 7) * 8;                                   \
        *(int4*)(&As[r * LDPA + kg]) = sa[i];                               \
    }                                                                       \
    _Pragma("unroll")                                                       \
    for (int i = 0; i < 2; ++i) {                                           \
        int c = t + i * 512;                                                \
        int r = c >> 4, kq = (c & 15) * 4;                                  \
        ushort4 u;                                                          \
        u.x = f2bf(sb[i].x); u.y = f2bf(sb[i].y);                           \
        u.z = f2bf(sb[i].z); u.w = f2bf(sb[i].w);                           \
        *(ushort4*)(&Bs[r * LDPA + kq]) = u;                                \
    }
#define COMPUTE()                                                           \
    {                                                                       \
        v8bf af[4][2], bfr[2][2];                                           \
        _Pragma("unroll")                                                   \
        for (int m = 0; m < 4; ++m)                                         \
            _Pragma("unroll")                                               \
            for (int kk = 0; kk < 2; ++kk)                                  \
                af[m][kk] = *(const v8bf*)(&As[(wr*64 + m*16 + frow) * LDPA + kk*32 + fk]); \
        _Pragma("unroll")                                                   \
        for (int n = 0; n < 2; ++n)                                         \
            _Pragma("unroll")                                               \
            for (int kk = 0; kk < 2; ++kk)                                  \
                bfr[n][kk] = *(const v8bf*)(&Bs[(wc*32 + n*16 + frow) * LDPA + kk*32 + fk]); \
        _Pragma("unroll")                                                   \
        for (int kk = 0; kk < 2; ++kk)                                      \
            _Pragma("unroll")                                               \
            for (int m = 0; m < 4; ++m)                                     \
                _Pragma("unroll")                                           \
                for (int n = 0; n < 2; ++n)                                 \
                    acc[m][n] = __builtin_amdgcn_mfma_f32_16x16x32_bf16(af[m][kk], bfr[n][kk], acc[m][n], 0, 0, 0); \
    }

    for (int rep = 0; rep < 3; ++rep) {
        LOAD_A(ra0, 0)      LOAD_B(rb0, 0)
        LOAD_A(ra1, GBK)    LOAD_B(rb1, GBK)

        for (int it = 0; it < NKIT; it += 2) {
            WRITE_LDS(ra0, rb0)
            __syncthreads();
            if (it + 2 < NKIT) { LOAD_A(ra0, (it + 2) * GBK) LOAD_B(rb0, (it + 2) * GBK) }
            COMPUTE()
            __syncthreads();
            WRITE_LDS(ra1, rb1)
            __syncthreads();
            if (it + 3 < NKIT) { LOAD_A(ra1, (it + 3) * GBK) LOAD_B(rb1, (it + 3) * GBK) }
            COMPUTE()
            __syncthreads();
        }
    }

    const float third = 1.0f / 3.0f;
    const int crow = wr * 64 + (lane >> 4) * 4;
    const int ccol = col0 + wc * 32 + (lane & 15);
    #pragma unroll
    for (int n = 0; n < 2; ++n) {
        int col = ccol + n * 16;
        if (col < C_) {
            float bv = bias[col];
            #pragma unroll
            for (int m = 0; m < 4; ++m)
                #pragma unroll
                for (int r = 0; r < 4; ++r)
                    out[(size_t)(crow + m*16 + r) * C_ + col] = acc[m][n][r] * third + bv;
        }
    }
#undef LOAD_A
#undef LOAD_B
#undef WRITE_LDS
#undef COMPUTE
}

// ---------------------------------------------------------------------------
extern "C" void kernel_launch(void* const* d_in, const int* in_sizes, int n_in,
                              void* d_out, int out_size, void* d_ws, size_t ws_size,
                              hipStream_t stream) {
    const float* seq        = (const float*)d_in[0];
    const int*   head_index = (const int*)  d_in[1];
    const int*   start      = (const int*)  d_in[2];
    const int*   end        = (const int*)  d_in[3];
    const float* W          = (const float*)d_in[4];
    const float* bias       = (const float*)d_in[5];
    float*       out        = (float*)d_out;

    unsigned short* feats = (unsigned short*)d_ws;   // B_*K_ bf16 = 1.18 MB

    feats_gather<<<dim3(B_), dim3(512), 0, stream>>>(seq, head_index, start, end, feats);
    mfma_gemm<<<dim3(162), dim3(512), 0, stream>>>(feats, W, bias, out);
}

// Round 8
// 117.313 us; speedup vs baseline: 2.9289x; 2.9289x over previous
//
#include <hip/hip_runtime.h>

#define B_ 256
#define L_ 512
#define D_ 768
#define C_ 10331
#define K_ 2304           // 3*D
#define CPAD 10368        // 162*64
#define KSPLIT 2
#define KSL (K_ / KSPLIT) // 1152
#define GBK 64
#define NKIT (KSL / GBK)  // 18
#define LDPA 72           // padded LDS row (bf16 elems)

using v8bf = __attribute__((ext_vector_type(8))) __bf16;
using v4f  = __attribute__((ext_vector_type(4))) float;

__device__ __forceinline__ unsigned short f2bf(float f) {
    unsigned int u = __float_as_uint(f);
    unsigned int r = (u + 0x7FFFu + ((u >> 16) & 1u)) >> 16;   // RNE
    return (unsigned short)r;
}

__device__ __forceinline__ void fma4(float4& a, float w, const float4& v) {
    a.x = fmaf(w, v.x, a.x); a.y = fmaf(w, v.y, a.y);
    a.z = fmaf(w, v.z, a.z); a.w = fmaf(w, v.w, a.w);
}

// ---------------------------------------------------------------------------
// Kernel 1: count-based gather + masked means -> feats (B, 3D) bf16.
// (r6 production version: single streaming pass, rows deduped & ascending.)
// ---------------------------------------------------------------------------
__global__ __launch_bounds__(512) void feats_gather(
    const float* __restrict__ seq,        // (B, L, D)
    const int*   __restrict__ head_index, // (B, L)
    const int*   __restrict__ start,
    const int*   __restrict__ end,
    unsigned short* __restrict__ feats)   // (B, 3D) bf16
{
    const int b    = blockIdx.x;
    const int t    = threadIdx.x;
    const int lane = t & 63;
    const int wave = t >> 6;              // 0..7

    __shared__ int idx_sh[L_];
    __shared__ int cnt_sh[3][L_];
    __shared__ int list_sh[L_];
    __shared__ int nz_sh, nlist_sh;
    __shared__ float4 red_sh[8][3][192];  // 72 KB

    if (t == 0) nz_sh = 0;
    cnt_sh[0][t] = 0; cnt_sh[1][t] = 0; cnt_sh[2][t] = 0;
    const int v = head_index[b * L_ + t];
    idx_sh[t] = v;
    unsigned long long ball = __ballot(v != 0);
    __syncthreads();
    if (lane == 0) atomicAdd(&nz_sh, (int)__popcll(ball));
    __syncthreads();

    const int right_len = nz_sh;
    const int s = start[b];
    const int e = end[b];

    if (t < right_len) {
        int r = (t < s) ? 0 : ((t < e) ? 1 : 2);
        atomicAdd(&cnt_sh[r][v], 1);
    }
    __syncthreads();

    if (wave == 0) {
        int maskbits = 0, csum = 0;
        const int j0 = lane * 8;
        #pragma unroll
        for (int k = 0; k < 8; ++k) {
            int j = j0 + k;
            if (cnt_sh[0][j] | cnt_sh[1][j] | cnt_sh[2][j]) { maskbits |= (1 << k); ++csum; }
        }
        int incl = csum;
        #pragma unroll
        for (int off = 1; off < 64; off <<= 1) {
            int x = __shfl_up(incl, off, 64);
            if (lane >= off) incl += x;
        }
        int pos = incl - csum;
        #pragma unroll
        for (int k = 0; k < 8; ++k)
            if (maskbits & (1 << k)) list_sh[pos++] = j0 + k;
        if (lane == 63) nlist_sh = incl;
    }
    __syncthreads();

    const int nlist = nlist_sh;
    const int nl = s, nm = e - s, nr = right_len - e;
    const float rs0 = (nl > 0) ? 1.0f / (float)nl : 0.0f;
    const float rs1 = (nm > 0) ? 1.0f / (float)nm : 0.0f;
    const float rs2 = (nr > 0) ? 1.0f / (float)nr : 0.0f;

    const float4* seqb4 = reinterpret_cast<const float4*>(seq + (size_t)b * L_ * D_);

    float4 acc[3][3];
    #pragma unroll
    for (int r = 0; r < 3; ++r)
        #pragma unroll
        for (int jj = 0; jj < 3; ++jj)
            acc[r][jj] = make_float4(0.f, 0.f, 0.f, 0.f);

    int i = wave;
    for (; i + 8 < nlist; i += 16) {
        const int ja = list_sh[i], jb = list_sh[i + 8];
        const float4* rowa = seqb4 + (size_t)ja * 192;
        const float4* rowb = seqb4 + (size_t)jb * 192;
        float wa0 = (float)cnt_sh[0][ja] * rs0;
        float wa1 = (float)cnt_sh[1][ja] * rs1;
        float wa2 = (float)cnt_sh[2][ja] * rs2;
        float wb0 = (float)cnt_sh[0][jb] * rs0;
        float wb1 = (float)cnt_sh[1][jb] * rs1;
        float wb2 = (float)cnt_sh[2][jb] * rs2;
        #pragma unroll
        for (int jj = 0; jj < 3; ++jj) {
            float4 va = rowa[jj * 64 + lane];
            float4 vb = rowb[jj * 64 + lane];
            fma4(acc[0][jj], wa0, va); fma4(acc[1][jj], wa1, va); fma4(acc[2][jj], wa2, va);
            fma4(acc[0][jj], wb0, vb); fma4(acc[1][jj], wb1, vb); fma4(acc[2][jj], wb2, vb);
        }
    }
    if (i < nlist) {
        const int ja = list_sh[i];
        const float4* rowa = seqb4 + (size_t)ja * 192;
        float wa0 = (float)cnt_sh[0][ja] * rs0;
        float wa1 = (float)cnt_sh[1][ja] * rs1;
        float wa2 = (float)cnt_sh[2][ja] * rs2;
        #pragma unroll
        for (int jj = 0; jj < 3; ++jj) {
            float4 va = rowa[jj * 64 + lane];
            fma4(acc[0][jj], wa0, va); fma4(acc[1][jj], wa1, va); fma4(acc[2][jj], wa2, va);
        }
    }

    #pragma unroll
    for (int r = 0; r < 3; ++r)
        #pragma unroll
        for (int jj = 0; jj < 3; ++jj)
            red_sh[wave][r][jj * 64 + lane] = acc[r][jj];
    __syncthreads();

    for (int w = t; w < 576; w += 512) {
        int reg = w / 192, pos = w - reg * 192;
        float4 sum = red_sh[0][reg][pos];
        #pragma unroll
        for (int wv = 1; wv < 8; ++wv) {
            float4 x = red_sh[wv][reg][pos];
            sum.x += x.x; sum.y += x.y; sum.z += x.z; sum.w += x.w;
        }
        ushort4 u;
        u.x = f2bf(sum.x); u.y = f2bf(sum.y); u.z = f2bf(sum.z); u.w = f2bf(sum.w);
        *(ushort4*)(&feats[(size_t)b * K_ + reg * D_ + pos * 4]) = u;
    }
}

// ---------------------------------------------------------------------------
// Kernel 2: part[ks] = feats(bf16) @ W[:,kslice]^T.
// A-fragments loaded DIRECTLY from global (L2-resident, 64B-coherent across
// lanes) — no A LDS staging. Only W goes through LDS: double-buffered 9.2KB
// each, 1 barrier per K-tile, 2-slot register prefetch.
// tile 256x64, BK=64, 512 thr (8 waves = 4 row x 2 col), grid (162, KSPLIT).
// ---------------------------------------------------------------------------
__global__ __launch_bounds__(512, 4) void mfma_gemm(
    const unsigned short* __restrict__ A,  // (B_, K_) bf16
    const float* __restrict__ W,           // (C_, K_) fp32
    float*       __restrict__ part)        // (KSPLIT, B_, CPAD) f32
{
    __shared__ unsigned short Bs0[64 * LDPA];   // 9216 B
    __shared__ unsigned short Bs1[64 * LDPA];   // 9216 B

    const int t    = threadIdx.x;
    const int lane = t & 63;
    const int wave = t >> 6;
    const int wr   = wave >> 1;      // 0..3
    const int wc   = wave & 1;       // 0..1
    const int col0 = blockIdx.x * 64;
    const int kbase = blockIdx.y * KSL;

    const int frow = lane & 15;
    const int fk   = (lane >> 4) * 8;

    // per-wave A base: row = wr*64 + m*16 + frow
    const unsigned short* a_base = A + (size_t)(wr * 64 + frow) * K_ + kbase + fk;

    v4f acc[4][2] = {};
    float4 rb0[2], rb1[2];

#define LOAD_B(dst, k0)                                                     \
    _Pragma("unroll")                                                       \
    for (int i = 0; i < 2; ++i) {                                           \
        int c = t + i * 512;                                                \
        int r = c >> 4, kq = (c & 15) * 4;                                  \
        int col = col0 + r;                                                 \
        dst[i] = (col < C_) ? *(const float4*)(W + (size_t)col * K_ + kbase + (k0) + kq) \
                            : make_float4(0.f, 0.f, 0.f, 0.f);              \
    }
#define WRITE_B(BSBUF, src)                                                 \
    _Pragma("unroll")                                                       \
    for (int i = 0; i < 2; ++i) {                                           \
        int c = t + i * 512;                                                \
        int r = c >> 4, kq = (c & 15) * 4;                                  \
        ushort4 u;                                                          \
        u.x = f2bf(src[i].x); u.y = f2bf(src[i].y);                         \
        u.z = f2bf(src[i].z); u.w = f2bf(src[i].w);                         \
        *(ushort4*)(&BSBUF[r * LDPA + kq]) = u;                             \
    }
#define COMPUTE(BSBUF, koff)                                                \
    {                                                                       \
        v8bf af[4][2], bfr[2][2];                                           \
        _Pragma("unroll")                                                   \
        for (int m = 0; m < 4; ++m)                                         \
            _Pragma("unroll")                                               \
            for (int kk = 0; kk < 2; ++kk)                                  \
                af[m][kk] = *(const v8bf*)(a_base + (size_t)m * 16 * K_ + (koff) + kk * 32); \
        _Pragma("unroll")                                                   \
        for (int n = 0; n < 2; ++n)                                         \
            _Pragma("unroll")                                               \
            for (int kk = 0; kk < 2; ++kk)                                  \
                bfr[n][kk] = *(const v8bf*)(&BSBUF[(wc*32 + n*16 + frow) * LDPA + kk*32 + fk]); \
        _Pragma("unroll")                                                   \
        for (int kk = 0; kk < 2; ++kk)                                      \
            _Pragma("unroll")                                               \
            for (int m = 0; m < 4; ++m)                                     \
                _Pragma("unroll")                                           \
                for (int n = 0; n < 2; ++n)                                 \
                    acc[m][n] = __builtin_amdgcn_mfma_f32_16x16x32_bf16(af[m][kk], bfr[n][kk], acc[m][n], 0, 0, 0); \
    }

    LOAD_B(rb0, 0)
    LOAD_B(rb1, GBK)

    for (int it = 0; it < NKIT; it += 2) {
        WRITE_B(Bs0, rb0)
        __syncthreads();                       // Bs0 ready; also fences prev C1 vs next W1
        if (it + 2 < NKIT) { LOAD_B(rb0, (it + 2) * GBK) }
        COMPUTE(Bs0, it * GBK)
        WRITE_B(Bs1, rb1)
        __syncthreads();                       // Bs1 ready; also fences C0 vs next W0
        if (it + 3 < NKIT) { LOAD_B(rb1, (it + 3) * GBK) }
        COMPUTE(Bs1, (it + 1) * GBK)
    }

    // ---- epilogue: fp32 partial, padded C (unguarded) ----
    float* p = part + (size_t)blockIdx.y * B_ * CPAD;
    const int crow = wr * 64 + (lane >> 4) * 4;
    const int ccol = col0 + wc * 32 + (lane & 15);
    #pragma unroll
    for (int n = 0; n < 2; ++n) {
        int col = ccol + n * 16;
        #pragma unroll
        for (int m = 0; m < 4; ++m)
            #pragma unroll
            for (int r = 0; r < 4; ++r)
                p[(size_t)(crow + m*16 + r) * CPAD + col] = acc[m][n][r];
    }
#undef LOAD_B
#undef WRITE_B
#undef COMPUTE
}

// ---------------------------------------------------------------------------
// Kernel 3: out[b,c] = part[0][b][c] + part[1][b][c] + bias[c]
// ---------------------------------------------------------------------------
__global__ __launch_bounds__(256) void reduce_bias(
    const float* __restrict__ part,
    const float* __restrict__ bias,
    float*       __restrict__ out)
{
    const int row  = blockIdx.x >> 1;
    const int half = blockIdx.x & 1;
    const int t = threadIdx.x;
    const int NQ  = CPAD / 4;        // 2592
    const int NQ2 = NQ / 2;          // 1296

    const float4* p0 = (const float4*)(part + (size_t)0 * B_ * CPAD + (size_t)row * CPAD);
    const float4* p1 = (const float4*)(part + (size_t)1 * B_ * CPAD + (size_t)row * CPAD);
    float* orow = out + (size_t)row * C_;

    const int c4lo = half * NQ2, c4hi = c4lo + NQ2;
    for (int c4 = c4lo + t; c4 < c4hi; c4 += 256) {
        float4 a = p0[c4], b = p1[c4];
        float s0 = a.x + b.x;
        float s1 = a.y + b.y;
        float s2 = a.z + b.z;
        float s3 = a.w + b.w;
        int cc = c4 * 4;
        if (cc + 3 < C_) {
            float4 bv = ((const float4*)bias)[c4];
            orow[cc + 0] = s0 + bv.x;
            orow[cc + 1] = s1 + bv.y;
            orow[cc + 2] = s2 + bv.z;
            orow[cc + 3] = s3 + bv.w;
        } else {
            if (cc + 0 < C_) orow[cc + 0] = s0 + bias[cc + 0];
            if (cc + 1 < C_) orow[cc + 1] = s1 + bias[cc + 1];
            if (cc + 2 < C_) orow[cc + 2] = s2 + bias[cc + 2];
            if (cc + 3 < C_) orow[cc + 3] = s3 + bias[cc + 3];
        }
    }
}

// ---------------------------------------------------------------------------
extern "C" void kernel_launch(void* const* d_in, const int* in_sizes, int n_in,
                              void* d_out, int out_size, void* d_ws, size_t ws_size,
                              hipStream_t stream) {
    const float* seq        = (const float*)d_in[0];
    const int*   head_index = (const int*)  d_in[1];
    const int*   start      = (const int*)  d_in[2];
    const int*   end        = (const int*)  d_in[3];
    const float* W          = (const float*)d_in[4];
    const float* bias       = (const float*)d_in[5];
    float*       out        = (float*)d_out;

    unsigned short* feats = (unsigned short*)d_ws;                 // 1.18 MB
    float* part = (float*)((char*)d_ws + ((size_t)2 << 20));       // 21.2 MB

    feats_gather<<<dim3(B_), dim3(512), 0, stream>>>(seq, head_index, start, end, feats);

    dim3 grid(CPAD / 64, KSPLIT);   // (162, 2) = 324 blocks
    mfma_gemm<<<grid, dim3(512), 0, stream>>>(feats, W, part);

    reduce_bias<<<dim3(B_ * 2), dim3(256), 0, stream>>>(part, bias, out);
}

// Round 9
// 86.833 us; speedup vs baseline: 3.9571x; 1.3510x over previous
//
#include <hip/hip_runtime.h>

#define B_ 256
#define L_ 512
#define D_ 768
#define C_ 10331
#define K_ 2304           // 3*D
#define CPAD 10368        // 81*128
#define KSPLIT 2
#define KSL (K_ / KSPLIT) // 1152
#define GBK 64
#define NKIT (KSL / GBK)  // 18
#define LDPA 72           // padded LDS row (bf16 elems)

using v8bf = __attribute__((ext_vector_type(8))) __bf16;
using v4f  = __attribute__((ext_vector_type(4))) float;

__device__ __forceinline__ unsigned short f2bf(float f) {
    unsigned int u = __float_as_uint(f);
    unsigned int r = (u + 0x7FFFu + ((u >> 16) & 1u)) >> 16;   // RNE
    return (unsigned short)r;
}

__device__ __forceinline__ void fma4(float4& a, float w, const float4& v) {
    a.x = fmaf(w, v.x, a.x); a.y = fmaf(w, v.y, a.y);
    a.z = fmaf(w, v.z, a.z); a.w = fmaf(w, v.w, a.w);
}

// ---------------------------------------------------------------------------
// Kernel 1: count-based gather + masked means -> feats (B, 3D) bf16.
// (unchanged r6 production version; measured ~13 us)
// ---------------------------------------------------------------------------
__global__ __launch_bounds__(512) void feats_gather(
    const float* __restrict__ seq,        // (B, L, D)
    const int*   __restrict__ head_index, // (B, L)
    const int*   __restrict__ start,
    const int*   __restrict__ end,
    unsigned short* __restrict__ feats)   // (B, 3D) bf16
{
    const int b    = blockIdx.x;
    const int t    = threadIdx.x;
    const int lane = t & 63;
    const int wave = t >> 6;              // 0..7

    __shared__ int idx_sh[L_];
    __shared__ int cnt_sh[3][L_];
    __shared__ int list_sh[L_];
    __shared__ int nz_sh, nlist_sh;
    __shared__ float4 red_sh[8][3][192];  // 72 KB

    if (t == 0) nz_sh = 0;
    cnt_sh[0][t] = 0; cnt_sh[1][t] = 0; cnt_sh[2][t] = 0;
    const int v = head_index[b * L_ + t];
    idx_sh[t] = v;
    unsigned long long ball = __ballot(v != 0);
    __syncthreads();
    if (lane == 0) atomicAdd(&nz_sh, (int)__popcll(ball));
    __syncthreads();

    const int right_len = nz_sh;
    const int s = start[b];
    const int e = end[b];

    if (t < right_len) {
        int r = (t < s) ? 0 : ((t < e) ? 1 : 2);
        atomicAdd(&cnt_sh[r][v], 1);
    }
    __syncthreads();

    if (wave == 0) {
        int maskbits = 0, csum = 0;
        const int j0 = lane * 8;
        #pragma unroll
        for (int k = 0; k < 8; ++k) {
            int j = j0 + k;
            if (cnt_sh[0][j] | cnt_sh[1][j] | cnt_sh[2][j]) { maskbits |= (1 << k); ++csum; }
        }
        int incl = csum;
        #pragma unroll
        for (int off = 1; off < 64; off <<= 1) {
            int x = __shfl_up(incl, off, 64);
            if (lane >= off) incl += x;
        }
        int pos = incl - csum;
        #pragma unroll
        for (int k = 0; k < 8; ++k)
            if (maskbits & (1 << k)) list_sh[pos++] = j0 + k;
        if (lane == 63) nlist_sh = incl;
    }
    __syncthreads();

    const int nlist = nlist_sh;
    const int nl = s, nm = e - s, nr = right_len - e;
    const float rs0 = (nl > 0) ? 1.0f / (float)nl : 0.0f;
    const float rs1 = (nm > 0) ? 1.0f / (float)nm : 0.0f;
    const float rs2 = (nr > 0) ? 1.0f / (float)nr : 0.0f;

    const float4* seqb4 = reinterpret_cast<const float4*>(seq + (size_t)b * L_ * D_);

    float4 acc[3][3];
    #pragma unroll
    for (int r = 0; r < 3; ++r)
        #pragma unroll
        for (int jj = 0; jj < 3; ++jj)
            acc[r][jj] = make_float4(0.f, 0.f, 0.f, 0.f);

    int i = wave;
    for (; i + 8 < nlist; i += 16) {
        const int ja = list_sh[i], jb = list_sh[i + 8];
        const float4* rowa = seqb4 + (size_t)ja * 192;
        const float4* rowb = seqb4 + (size_t)jb * 192;
        float wa0 = (float)cnt_sh[0][ja] * rs0;
        float wa1 = (float)cnt_sh[1][ja] * rs1;
        float wa2 = (float)cnt_sh[2][ja] * rs2;
        float wb0 = (float)cnt_sh[0][jb] * rs0;
        float wb1 = (float)cnt_sh[1][jb] * rs1;
        float wb2 = (float)cnt_sh[2][jb] * rs2;
        #pragma unroll
        for (int jj = 0; jj < 3; ++jj) {
            float4 va = rowa[jj * 64 + lane];
            float4 vb = rowb[jj * 64 + lane];
            fma4(acc[0][jj], wa0, va); fma4(acc[1][jj], wa1, va); fma4(acc[2][jj], wa2, va);
            fma4(acc[0][jj], wb0, vb); fma4(acc[1][jj], wb1, vb); fma4(acc[2][jj], wb2, vb);
        }
    }
    if (i < nlist) {
        const int ja = list_sh[i];
        const float4* rowa = seqb4 + (size_t)ja * 192;
        float wa0 = (float)cnt_sh[0][ja] * rs0;
        float wa1 = (float)cnt_sh[1][ja] * rs1;
        float wa2 = (float)cnt_sh[2][ja] * rs2;
        #pragma unroll
        for (int jj = 0; jj < 3; ++jj) {
            float4 va = rowa[jj * 64 + lane];
            fma4(acc[0][jj], wa0, va); fma4(acc[1][jj], wa1, va); fma4(acc[2][jj], wa2, va);
        }
    }

    #pragma unroll
    for (int r = 0; r < 3; ++r)
        #pragma unroll
        for (int jj = 0; jj < 3; ++jj)
            red_sh[wave][r][jj * 64 + lane] = acc[r][jj];
    __syncthreads();

    for (int w = t; w < 576; w += 512) {
        int reg = w / 192, pos = w - reg * 192;
        float4 sum = red_sh[0][reg][pos];
        #pragma unroll
        for (int wv = 1; wv < 8; ++wv) {
            float4 x = red_sh[wv][reg][pos];
            sum.x += x.x; sum.y += x.y; sum.z += x.z; sum.w += x.w;
        }
        ushort4 u;
        u.x = f2bf(sum.x); u.y = f2bf(sum.y); u.z = f2bf(sum.z); u.w = f2bf(sum.w);
        *(ushort4*)(&feats[(size_t)b * K_ + reg * D_ + pos * 4]) = u;
    }
}

// ---------------------------------------------------------------------------
// Kernel 2: part[ks] = feats(bf16) @ W[:,kslice]^T.
// 1024 thr, tile 256x128, 16 waves (8 row x 2 col; per wave m2,n4,kk2).
// A-frags: register double-buffer (afA/afB), prefetched 1 phase ahead from
// global (L2-resident). W: 2-phase reg prefetch -> bf16 LDS double buffer,
// 1 barrier per tile. grid (81, KSPLIT) = 162 blocks.
// ---------------------------------------------------------------------------
__global__ __launch_bounds__(1024, 4) void mfma_gemm(
    const unsigned short* __restrict__ A,  // (B_, K_) bf16
    const float* __restrict__ W,           // (C_, K_) fp32
    float*       __restrict__ part)        // (KSPLIT, B_, CPAD) f32
{
    __shared__ unsigned short Bs0[128 * LDPA];   // 18432 B
    __shared__ unsigned short Bs1[128 * LDPA];   // 18432 B

    const int t    = threadIdx.x;
    const int lane = t & 63;
    const int wave = t >> 6;         // 0..15
    const int wr   = wave >> 1;      // 0..7 : 32-row group
    const int wc   = wave & 1;       // 0..1 : 64-col group
    const int col0 = blockIdx.x * 128;
    const int kbase = blockIdx.y * KSL;

    const int frow = lane & 15;
    const int fk   = (lane >> 4) * 8;

    const unsigned short* a_base = A + (size_t)(wr * 32 + frow) * K_ + kbase + fk;

    v4f acc[2][4] = {};
    v8bf afA[2][2], afB[2][2];
    float4 rb0[2], rb1[2];

#define LOAD_AF(dst, k0)                                                    \
    _Pragma("unroll")                                                       \
    for (int m = 0; m < 2; ++m)                                             \
        _Pragma("unroll")                                                   \
        for (int kk = 0; kk < 2; ++kk)                                      \
            dst[m][kk] = *(const v8bf*)(a_base + (size_t)m * 16 * K_ + (k0) + kk * 32);
#define LOAD_B(dst, k0)                                                     \
    _Pragma("unroll")                                                       \
    for (int i = 0; i < 2; ++i) {                                           \
        int c = t + i * 1024;                                               \
        int r = c >> 4, kq = (c & 15) * 4;                                  \
        int col = col0 + r;                                                 \
        dst[i] = (col < C_) ? *(const float4*)(W + (size_t)col * K_ + kbase + (k0) + kq) \
                            : make_float4(0.f, 0.f, 0.f, 0.f);              \
    }
#define WRITE_B(BSBUF, src)                                                 \
    _Pragma("unroll")                                                       \
    for (int i = 0; i < 2; ++i) {                                           \
        int c = t + i * 1024;                                               \
        int r = c >> 4, kq = (c & 15) * 4;                                  \
        ushort4 u;                                                          \
        u.x = f2bf(src[i].x); u.y = f2bf(src[i].y);                         \
        u.z = f2bf(src[i].z); u.w = f2bf(src[i].w);                         \
        *(ushort4*)(&BSBUF[r * LDPA + kq]) = u;                             \
    }
#define COMPUTE(AF, BSBUF)                                                  \
    {                                                                       \
        v8bf bfr[4][2];                                                     \
        _Pragma("unroll")                                                   \
        for (int n = 0; n < 4; ++n)                                         \
            _Pragma("unroll")                                               \
            for (int kk = 0; kk < 2; ++kk)                                  \
                bfr[n][kk] = *(const v8bf*)(&BSBUF[(wc*64 + n*16 + frow) * LDPA + kk*32 + fk]); \
        _Pragma("unroll")                                                   \
        for (int kk = 0; kk < 2; ++kk)                                      \
            _Pragma("unroll")                                               \
            for (int m = 0; m < 2; ++m)                                     \
                _Pragma("unroll")                                           \
                for (int n = 0; n < 4; ++n)                                 \
                    acc[m][n] = __builtin_amdgcn_mfma_f32_16x16x32_bf16(AF[m][kk], bfr[n][kk], acc[m][n], 0, 0, 0); \
    }

    LOAD_AF(afA, 0)
    LOAD_B(rb0, 0)
    LOAD_B(rb1, GBK)

    for (int it = 0; it < NKIT; it += 2) {
        // ---- phase A: tile it ----
        WRITE_B(Bs0, rb0)
        __syncthreads();                           // Bs0 ready
        if (it + 2 < NKIT) { LOAD_B(rb0, (it + 2) * GBK) }
        LOAD_AF(afB, (it + 1) * GBK)               // A prefetch (it+1 < NKIT always)
        COMPUTE(afA, Bs0)
        // ---- phase B: tile it+1 ----
        WRITE_B(Bs1, rb1)
        __syncthreads();                           // Bs1 ready
        if (it + 3 < NKIT) { LOAD_B(rb1, (it + 3) * GBK) }
        if (it + 2 < NKIT) { LOAD_AF(afA, (it + 2) * GBK) }
        COMPUTE(afB, Bs1)
    }

    // ---- epilogue: fp32 partial, padded C (unguarded) ----
    float* p = part + (size_t)blockIdx.y * B_ * CPAD;
    const int crow = wr * 32 + (lane >> 4) * 4;
    const int ccol = col0 + wc * 64 + (lane & 15);
    #pragma unroll
    for (int n = 0; n < 4; ++n) {
        int col = ccol + n * 16;
        #pragma unroll
        for (int m = 0; m < 2; ++m)
            #pragma unroll
            for (int r = 0; r < 4; ++r)
                p[(size_t)(crow + m*16 + r) * CPAD + col] = acc[m][n][r];
    }
#undef LOAD_AF
#undef LOAD_B
#undef WRITE_B
#undef COMPUTE
}

// ---------------------------------------------------------------------------
// Kernel 3: out[b,c] = part[0][b][c] + part[1][b][c] + bias[c]
// grid B_*4 (quarter-rows) for full-chip coverage.
// ---------------------------------------------------------------------------
__global__ __launch_bounds__(256) void reduce_bias(
    const float* __restrict__ part,
    const float* __restrict__ bias,
    float*       __restrict__ out)
{
    const int row = blockIdx.x >> 2;
    const int q   = blockIdx.x & 3;
    const int t = threadIdx.x;
    const int NQ  = CPAD / 4;        // 2592
    const int NQQ = NQ / 4;          // 648

    const float4* p0 = (const float4*)(part + (size_t)0 * B_ * CPAD + (size_t)row * CPAD);
    const float4* p1 = (const float4*)(part + (size_t)1 * B_ * CPAD + (size_t)row * CPAD);
    float* orow = out + (size_t)row * C_;

    const int c4lo = q * NQQ, c4hi = c4lo + NQQ;
    for (int c4 = c4lo + t; c4 < c4hi; c4 += 256) {
        float4 a = p0[c4], b = p1[c4];
        float s0 = a.x + b.x;
        float s1 = a.y + b.y;
        float s2 = a.z + b.z;
        float s3 = a.w + b.w;
        int cc = c4 * 4;
        if (cc + 3 < C_) {
            float4 bv = ((const float4*)bias)[c4];
            orow[cc + 0] = s0 + bv.x;
            orow[cc + 1] = s1 + bv.y;
            orow[cc + 2] = s2 + bv.z;
            orow[cc + 3] = s3 + bv.w;
        } else {
            if (cc + 0 < C_) orow[cc + 0] = s0 + bias[cc + 0];
            if (cc + 1 < C_) orow[cc + 1] = s1 + bias[cc + 1];
            if (cc + 2 < C_) orow[cc + 2] = s2 + bias[cc + 2];
            if (cc + 3 < C_) orow[cc + 3] = s3 + bias[cc + 3];
        }
    }
}

// ---------------------------------------------------------------------------
extern "C" void kernel_launch(void* const* d_in, const int* in_sizes, int n_in,
                              void* d_out, int out_size, void* d_ws, size_t ws_size,
                              hipStream_t stream) {
    const float* seq        = (const float*)d_in[0];
    const int*   head_index = (const int*)  d_in[1];
    const int*   start      = (const int*)  d_in[2];
    const int*   end        = (const int*)  d_in[3];
    const float* W          = (const float*)d_in[4];
    const float* bias       = (const float*)d_in[5];
    float*       out        = (float*)d_out;

    unsigned short* feats = (unsigned short*)d_ws;                 // 1.18 MB
    float* part = (float*)((char*)d_ws + ((size_t)2 << 20));       // 21.2 MB

    feats_gather<<<dim3(B_), dim3(512), 0, stream>>>(seq, head_index, start, end, feats);

    dim3 grid(CPAD / 128, KSPLIT);   // (81, 2) = 162 blocks
    mfma_gemm<<<grid, dim3(1024), 0, stream>>>(feats, W, part);

    reduce_bias<<<dim3(B_ * 4), dim3(256), 0, stream>>>(part, bias, out);
}

// Round 10
// 74.913 us; speedup vs baseline: 4.5867x; 1.1591x over previous
//
#include <hip/hip_runtime.h>

#define B_ 256
#define L_ 512
#define D_ 768
#define C_ 10331
#define K_ 2304           // 3*D
#define CPAD 10368        // 81*128
#define KSPLIT 3
#define KSL (K_ / KSPLIT) // 768
#define GBK 64
#define NKIT (KSL / GBK)  // 12
#define LDPA 72           // padded LDS row (bf16 elems)

using v8bf = __attribute__((ext_vector_type(8))) __bf16;
using v4f  = __attribute__((ext_vector_type(4))) float;

__device__ __forceinline__ unsigned short f2bf(float f) {
    unsigned int u = __float_as_uint(f);
    unsigned int r = (u + 0x7FFFu + ((u >> 16) & 1u)) >> 16;   // RNE
    return (unsigned short)r;
}

__device__ __forceinline__ void fma4(float4& a, float w, const float4& v) {
    a.x = fmaf(w, v.x, a.x); a.y = fmaf(w, v.y, a.y);
    a.z = fmaf(w, v.z, a.z); a.w = fmaf(w, v.w, a.w);
}

// ---------------------------------------------------------------------------
// Kernel 1: count-based gather + masked means -> feats (B, 3D) bf16.
// (unchanged; ~13 us, near its HBM/L3 floor)
// ---------------------------------------------------------------------------
__global__ __launch_bounds__(512) void feats_gather(
    const float* __restrict__ seq,        // (B, L, D)
    const int*   __restrict__ head_index, // (B, L)
    const int*   __restrict__ start,
    const int*   __restrict__ end,
    unsigned short* __restrict__ feats)   // (B, 3D) bf16
{
    const int b    = blockIdx.x;
    const int t    = threadIdx.x;
    const int lane = t & 63;
    const int wave = t >> 6;              // 0..7

    __shared__ int idx_sh[L_];
    __shared__ int cnt_sh[3][L_];
    __shared__ int list_sh[L_];
    __shared__ int nz_sh, nlist_sh;
    __shared__ float4 red_sh[8][3][192];  // 72 KB

    if (t == 0) nz_sh = 0;
    cnt_sh[0][t] = 0; cnt_sh[1][t] = 0; cnt_sh[2][t] = 0;
    const int v = head_index[b * L_ + t];
    idx_sh[t] = v;
    unsigned long long ball = __ballot(v != 0);
    __syncthreads();
    if (lane == 0) atomicAdd(&nz_sh, (int)__popcll(ball));
    __syncthreads();

    const int right_len = nz_sh;
    const int s = start[b];
    const int e = end[b];

    if (t < right_len) {
        int r = (t < s) ? 0 : ((t < e) ? 1 : 2);
        atomicAdd(&cnt_sh[r][v], 1);
    }
    __syncthreads();

    if (wave == 0) {
        int maskbits = 0, csum = 0;
        const int j0 = lane * 8;
        #pragma unroll
        for (int k = 0; k < 8; ++k) {
            int j = j0 + k;
            if (cnt_sh[0][j] | cnt_sh[1][j] | cnt_sh[2][j]) { maskbits |= (1 << k); ++csum; }
        }
        int incl = csum;
        #pragma unroll
        for (int off = 1; off < 64; off <<= 1) {
            int x = __shfl_up(incl, off, 64);
            if (lane >= off) incl += x;
        }
        int pos = incl - csum;
        #pragma unroll
        for (int k = 0; k < 8; ++k)
            if (maskbits & (1 << k)) list_sh[pos++] = j0 + k;
        if (lane == 63) nlist_sh = incl;
    }
    __syncthreads();

    const int nlist = nlist_sh;
    const int nl = s, nm = e - s, nr = right_len - e;
    const float rs0 = (nl > 0) ? 1.0f / (float)nl : 0.0f;
    const float rs1 = (nm > 0) ? 1.0f / (float)nm : 0.0f;
    const float rs2 = (nr > 0) ? 1.0f / (float)nr : 0.0f;

    const float4* seqb4 = reinterpret_cast<const float4*>(seq + (size_t)b * L_ * D_);

    float4 acc[3][3];
    #pragma unroll
    for (int r = 0; r < 3; ++r)
        #pragma unroll
        for (int jj = 0; jj < 3; ++jj)
            acc[r][jj] = make_float4(0.f, 0.f, 0.f, 0.f);

    int i = wave;
    for (; i + 8 < nlist; i += 16) {
        const int ja = list_sh[i], jb = list_sh[i + 8];
        const float4* rowa = seqb4 + (size_t)ja * 192;
        const float4* rowb = seqb4 + (size_t)jb * 192;
        float wa0 = (float)cnt_sh[0][ja] * rs0;
        float wa1 = (float)cnt_sh[1][ja] * rs1;
        float wa2 = (float)cnt_sh[2][ja] * rs2;
        float wb0 = (float)cnt_sh[0][jb] * rs0;
        float wb1 = (float)cnt_sh[1][jb] * rs1;
        float wb2 = (float)cnt_sh[2][jb] * rs2;
        #pragma unroll
        for (int jj = 0; jj < 3; ++jj) {
            float4 va = rowa[jj * 64 + lane];
            float4 vb = rowb[jj * 64 + lane];
            fma4(acc[0][jj], wa0, va); fma4(acc[1][jj], wa1, va); fma4(acc[2][jj], wa2, va);
            fma4(acc[0][jj], wb0, vb); fma4(acc[1][jj], wb1, vb); fma4(acc[2][jj], wb2, vb);
        }
    }
    if (i < nlist) {
        const int ja = list_sh[i];
        const float4* rowa = seqb4 + (size_t)ja * 192;
        float wa0 = (float)cnt_sh[0][ja] * rs0;
        float wa1 = (float)cnt_sh[1][ja] * rs1;
        float wa2 = (float)cnt_sh[2][ja] * rs2;
        #pragma unroll
        for (int jj = 0; jj < 3; ++jj) {
            float4 va = rowa[jj * 64 + lane];
            fma4(acc[0][jj], wa0, va); fma4(acc[1][jj], wa1, va); fma4(acc[2][jj], wa2, va);
        }
    }

    #pragma unroll
    for (int r = 0; r < 3; ++r)
        #pragma unroll
        for (int jj = 0; jj < 3; ++jj)
            red_sh[wave][r][jj * 64 + lane] = acc[r][jj];
    __syncthreads();

    for (int w = t; w < 576; w += 512) {
        int reg = w / 192, pos = w - reg * 192;
        float4 sum = red_sh[0][reg][pos];
        #pragma unroll
        for (int wv = 1; wv < 8; ++wv) {
            float4 x = red_sh[wv][reg][pos];
            sum.x += x.x; sum.y += x.y; sum.z += x.z; sum.w += x.w;
        }
        ushort4 u;
        u.x = f2bf(sum.x); u.y = f2bf(sum.y); u.z = f2bf(sum.z); u.w = f2bf(sum.w);
        *(ushort4*)(&feats[(size_t)b * K_ + reg * D_ + pos * 4]) = u;
    }
}

// ---------------------------------------------------------------------------
// Kernel 2: part[ks] = feats(bf16) @ W[:,kslice]^T.
// 1024 thr, tile 256x128, 16 waves (8 row x 2 col; per wave m2,n4,kk2).
// A-frags: register double-buffer, prefetched 1 phase ahead and issued
// BEFORE the W prefetch each phase (so the A vmcnt-wait leaves the W stream
// in flight). W: 2-phase reg prefetch -> bf16 LDS double buffer, 1 barrier
// per tile. grid (81, KSPLIT=3) = 243 blocks (full chip).
// ---------------------------------------------------------------------------
__global__ __launch_bounds__(1024, 4) void mfma_gemm(
    const unsigned short* __restrict__ A,  // (B_, K_) bf16
    const float* __restrict__ W,           // (C_, K_) fp32
    float*       __restrict__ part)        // (KSPLIT, B_, CPAD) f32
{
    __shared__ unsigned short Bs0[128 * LDPA];   // 18432 B
    __shared__ unsigned short Bs1[128 * LDPA];   // 18432 B

    const int t    = threadIdx.x;
    const int lane = t & 63;
    const int wave = t >> 6;         // 0..15
    const int wr   = wave >> 1;      // 0..7 : 32-row group
    const int wc   = wave & 1;       // 0..1 : 64-col group
    const int col0 = blockIdx.x * 128;
    const int kbase = blockIdx.y * KSL;

    const int frow = lane & 15;
    const int fk   = (lane >> 4) * 8;

    const unsigned short* a_base = A + (size_t)(wr * 32 + frow) * K_ + kbase + fk;

    v4f acc[2][4] = {};
    v8bf afA[2][2], afB[2][2];
    float4 rb0[2], rb1[2];

#define LOAD_AF(dst, k0)                                                    \
    _Pragma("unroll")                                                       \
    for (int m = 0; m < 2; ++m)                                             \
        _Pragma("unroll")                                                   \
        for (int kk = 0; kk < 2; ++kk)                                      \
            dst[m][kk] = *(const v8bf*)(a_base + (size_t)m * 16 * K_ + (k0) + kk * 32);
#define LOAD_B(dst, k0)                                                     \
    _Pragma("unroll")                                                       \
    for (int i = 0; i < 2; ++i) {                                           \
        int c = t + i * 1024;                                               \
        int r = c >> 4, kq = (c & 15) * 4;                                  \
        int col = col0 + r;                                                 \
        dst[i] = (col < C_) ? *(const float4*)(W + (size_t)col * K_ + kbase + (k0) + kq) \
                            : make_float4(0.f, 0.f, 0.f, 0.f);              \
    }
#define WRITE_B(BSBUF, src)                                                 \
    _Pragma("unroll")                                                       \
    for (int i = 0; i < 2; ++i) {                                           \
        int c = t + i * 1024;                                               \
        int r = c >> 4, kq = (c & 15) * 4;                                  \
        ushort4 u;                                                          \
        u.x = f2bf(src[i].x); u.y = f2bf(src[i].y);                         \
        u.z = f2bf(src[i].z); u.w = f2bf(src[i].w);                         \
        *(ushort4*)(&BSBUF[r * LDPA + kq]) = u;                             \
    }
#define COMPUTE(AF, BSBUF)                                                  \
    {                                                                       \
        v8bf bfr[4][2];                                                     \
        _Pragma("unroll")                                                   \
        for (int n = 0; n < 4; ++n)                                         \
            _Pragma("unroll")                                               \
            for (int kk = 0; kk < 2; ++kk)                                  \
                bfr[n][kk] = *(const v8bf*)(&BSBUF[(wc*64 + n*16 + frow) * LDPA + kk*32 + fk]); \
        _Pragma("unroll")                                                   \
        for (int kk = 0; kk < 2; ++kk)                                      \
            _Pragma("unroll")                                               \
            for (int m = 0; m < 2; ++m)                                     \
                _Pragma("unroll")                                           \
                for (int n = 0; n < 4; ++n)                                 \
                    acc[m][n] = __builtin_amdgcn_mfma_f32_16x16x32_bf16(AF[m][kk], bfr[n][kk], acc[m][n], 0, 0, 0); \
    }

    LOAD_AF(afA, 0)
    LOAD_B(rb0, 0)
    LOAD_B(rb1, GBK)

    for (int it = 0; it < NKIT; it += 2) {
        // ---- phase A: tile it ----
        WRITE_B(Bs0, rb0)
        __syncthreads();                           // Bs0 ready
        LOAD_AF(afB, (it + 1) * GBK)               // A first (consumed next phase)
        if (it + 2 < NKIT) { LOAD_B(rb0, (it + 2) * GBK) }   // W after (2 phases out)
        COMPUTE(afA, Bs0)
        // ---- phase B: tile it+1 ----
        WRITE_B(Bs1, rb1)
        __syncthreads();                           // Bs1 ready
        if (it + 2 < NKIT) { LOAD_AF(afA, (it + 2) * GBK) }
        if (it + 3 < NKIT) { LOAD_B(rb1, (it + 3) * GBK) }
        COMPUTE(afB, Bs1)
    }

    // ---- epilogue: fp32 partial, padded C (unguarded) ----
    float* p = part + (size_t)blockIdx.y * B_ * CPAD;
    const int crow = wr * 32 + (lane >> 4) * 4;
    const int ccol = col0 + wc * 64 + (lane & 15);
    #pragma unroll
    for (int n = 0; n < 4; ++n) {
        int col = ccol + n * 16;
        #pragma unroll
        for (int m = 0; m < 2; ++m)
            #pragma unroll
            for (int r = 0; r < 4; ++r)
                p[(size_t)(crow + m*16 + r) * CPAD + col] = acc[m][n][r];
    }
#undef LOAD_AF
#undef LOAD_B
#undef WRITE_B
#undef COMPUTE
}

// ---------------------------------------------------------------------------
// Kernel 3: out[b,c] = sum_s part[s][b][c] + bias[c]; grid B_*4 quarter-rows.
// ---------------------------------------------------------------------------
__global__ __launch_bounds__(256) void reduce_bias(
    const float* __restrict__ part,
    const float* __restrict__ bias,
    float*       __restrict__ out)
{
    const int row = blockIdx.x >> 2;
    const int q   = blockIdx.x & 3;
    const int t = threadIdx.x;
    const int NQ  = CPAD / 4;        // 2592
    const int NQQ = NQ / 4;          // 648

    const float4* p0 = (const float4*)(part + (size_t)0 * B_ * CPAD + (size_t)row * CPAD);
    const float4* p1 = (const float4*)(part + (size_t)1 * B_ * CPAD + (size_t)row * CPAD);
    const float4* p2 = (const float4*)(part + (size_t)2 * B_ * CPAD + (size_t)row * CPAD);
    float* orow = out + (size_t)row * C_;

    const int c4lo = q * NQQ, c4hi = c4lo + NQQ;
    for (int c4 = c4lo + t; c4 < c4hi; c4 += 256) {
        float4 a = p0[c4], b = p1[c4], c = p2[c4];
        float s0 = a.x + b.x + c.x;
        float s1 = a.y + b.y + c.y;
        float s2 = a.z + b.z + c.z;
        float s3 = a.w + b.w + c.w;
        int cc = c4 * 4;
        if (cc + 3 < C_) {
            float4 bv = ((const float4*)bias)[c4];
            orow[cc + 0] = s0 + bv.x;
            orow[cc + 1] = s1 + bv.y;
            orow[cc + 2] = s2 + bv.z;
            orow[cc + 3] = s3 + bv.w;
        } else {
            if (cc + 0 < C_) orow[cc + 0] = s0 + bias[cc + 0];
            if (cc + 1 < C_) orow[cc + 1] = s1 + bias[cc + 1];
            if (cc + 2 < C_) orow[cc + 2] = s2 + bias[cc + 2];
            if (cc + 3 < C_) orow[cc + 3] = s3 + bias[cc + 3];
        }
    }
}

// ---------------------------------------------------------------------------
extern "C" void kernel_launch(void* const* d_in, const int* in_sizes, int n_in,
                              void* d_out, int out_size, void* d_ws, size_t ws_size,
                              hipStream_t stream) {
    const float* seq        = (const float*)d_in[0];
    const int*   head_index = (const int*)  d_in[1];
    const int*   start      = (const int*)  d_in[2];
    const int*   end        = (const int*)  d_in[3];
    const float* W          = (const float*)d_in[4];
    const float* bias       = (const float*)d_in[5];
    float*       out        = (float*)d_out;

    unsigned short* feats = (unsigned short*)d_ws;                 // 1.18 MB
    float* part = (float*)((char*)d_ws + ((size_t)2 << 20));       // 31.9 MB

    feats_gather<<<dim3(B_), dim3(512), 0, stream>>>(seq, head_index, start, end, feats);

    dim3 grid(CPAD / 128, KSPLIT);   // (81, 3) = 243 blocks
    mfma_gemm<<<grid, dim3(1024), 0, stream>>>(feats, W, part);

    reduce_bias<<<dim3(B_ * 4), dim3(256), 0, stream>>>(part, bias, out);
}